// Round 9
// baseline (486.995 us; speedup 1.0000x reference)
//
#include <hip/hip_runtime.h>
#include <hip/hip_bf16.h>

// Dims
#define NB 4
#define NN 10000
#define NE 320000
#define BN 40000   // NB*NN
#define NL 7

typedef float f32x4 __attribute__((ext_vector_type(4)));
typedef __bf16 bf16x8 __attribute__((ext_vector_type(8)));

__device__ __forceinline__ float bf2f(unsigned short u){
  unsigned x = ((unsigned)u) << 16;
  return __builtin_bit_cast(float, x);
}
__device__ __forceinline__ unsigned short f2bf(float f){
  unsigned u = __builtin_bit_cast(unsigned, f);
  u += 0x7fffu + ((u >> 16) & 1u);
  return (unsigned short)(u >> 16);
}
__device__ __forceinline__ __bf16 f2b(float f){
  return __builtin_bit_cast(__bf16, f2bf(f));
}
__device__ __forceinline__ bf16x8 zero8(){
  uint4 z = make_uint4(0u,0u,0u,0u);
  return __builtin_bit_cast(bf16x8, z);
}
__device__ __forceinline__ bf16x8 ld8bf(const unsigned short* p){
  uint4 u = *(const uint4*)p;
  return __builtin_bit_cast(bf16x8, u);
}
__device__ __forceinline__ bf16x8 ld8f(const float* p){
  float4 a = *(const float4*)p;
  float4 b = *(const float4*)(p+4);
  bf16x8 r;
  r[0]=f2b(a.x); r[1]=f2b(a.y); r[2]=f2b(a.z); r[3]=f2b(a.w);
  r[4]=f2b(b.x); r[5]=f2b(b.y); r[6]=f2b(b.z); r[7]=f2b(b.w);
  return r;
}
__device__ __forceinline__ float frcp(float x){ return __builtin_amdgcn_rcpf(x); }
__device__ __forceinline__ float sigm(float x){ return frcp(1.f+__expf(-x)); }
__device__ __forceinline__ float tanh_(float x){ return 1.f - 2.f*frcp(__expf(2.f*x)+1.f); }
__device__ __forceinline__ float lrelu(float x){ return x > 0.f ? x : 0.01f*x; }

#define LDS_WAIT() asm volatile("s_waitcnt lgkmcnt(0)" ::: "memory")

// ---------------------------------------------------------------------------
// GRU: fused 16 steps, 1 wave per 16 (b,n) rows. hb wave-private; wave-local
// waitcnt ordering. 500 blocks x 5 waves (80 rows) — exactly <=2 blocks/CU
// (round-8's 625-block grid left 113 CUs with 3 resident blocks; wall tracked
// the 192-rows-per-CU stragglers). Do NOT hoist Wx fragments to registers
// (round-7: spills, 79->107 us).
// ---------------------------------------------------------------------------
__global__ __launch_bounds__(320, 2) void gru_kernel(
    const float* __restrict__ xd,   // [BN][256] f32 (T*DIN)
    const float* __restrict__ Wx,   // [16][192]
    const float* __restrict__ Wh,   // [64][192]
    const float* __restrict__ bx,   // [192]
    const float* __restrict__ bh,   // [192]
    float* __restrict__ rnn)        // [BN][64] f32 (max over T)
{
  __shared__ __attribute__((aligned(16))) unsigned short WhT[192][72];
  __shared__ __attribute__((aligned(16))) unsigned short WxT[192][40]; // k 16..31 zero
  __shared__ __attribute__((aligned(16))) unsigned short hb[5][16][72];
  int tid = threadIdx.x;
  int wave = tid >> 6, lane = tid & 63;
  int ln16 = lane & 15, quad = lane >> 4;

  for (int i = tid; i < 64*192; i += 320){
    int k = i / 192, n = i - k*192;
    WhT[n][k] = f2bf(Wh[i]);
  }
  for (int i = tid; i < 16*192; i += 320){
    int k = i / 192, n = i - k*192;
    WxT[n][k] = f2bf(Wx[i]);
    WxT[n][16+k] = 0;
  }
  for (int i = tid; i < 5*16*72; i += 320) ((unsigned short*)hb)[i] = 0;
  __syncthreads();   // the only block barrier

  int rowbase = blockIdx.x * 80 + wave * 16;

  bf16x8 whf[2][12];
  #pragma unroll
  for (int kt=0; kt<2; ++kt)
    #pragma unroll
    for (int nt=0; nt<12; ++nt)
      whf[kt][nt] = ld8bf(&WhT[nt*16 + ln16][kt*32 + quad*8]);

  float br_[4], bz_[4], bxn_[4], bhn_[4];
  #pragma unroll
  for (int j=0;j<4;++j){
    br_[j]  = bx[j*16+ln16]     + bh[j*16+ln16];
    bz_[j]  = bx[(4+j)*16+ln16] + bh[(4+j)*16+ln16];
    bxn_[j] = bx[(8+j)*16+ln16];
    bhn_[j] = bh[(8+j)*16+ln16];
  }

  f32x4 hprev[4], vmax[4];
  #pragma unroll
  for (int j=0;j<4;++j){
    hprev[j] = (f32x4){0.f,0.f,0.f,0.f};
    vmax[j]  = (f32x4){-1e30f,-1e30f,-1e30f,-1e30f};
  }

  const float* xrow = xd + (size_t)(rowbase + ln16) * 256;
  unsigned short* hrow = &hb[wave][ln16][0];

  bf16x8 axc = (quad < 2) ? ld8f(xrow + quad*8) : zero8();

  for (int t = 0; t < 16; ++t){
    bf16x8 axn = (t < 15 && quad < 2) ? ld8f(xrow + (t+1)*16 + quad*8) : zero8();
    bf16x8 ah0 = ld8bf(hrow + quad*8);
    bf16x8 ah1 = ld8bf(hrow + 32 + quad*8);

    #pragma unroll
    for (int j=0;j<4;++j){
      bf16x8 xr = ld8bf(&WxT[j*16+ln16][quad*8]);
      bf16x8 xz = ld8bf(&WxT[(4+j)*16+ln16][quad*8]);
      bf16x8 xn = ld8bf(&WxT[(8+j)*16+ln16][quad*8]);
      f32x4 ar = (f32x4){br_[j],br_[j],br_[j],br_[j]};
      ar = __builtin_amdgcn_mfma_f32_16x16x32_bf16(axc, xr, ar, 0,0,0);
      ar = __builtin_amdgcn_mfma_f32_16x16x32_bf16(ah0, whf[0][j], ar, 0,0,0);
      ar = __builtin_amdgcn_mfma_f32_16x16x32_bf16(ah1, whf[1][j], ar, 0,0,0);
      f32x4 az = (f32x4){bz_[j],bz_[j],bz_[j],bz_[j]};
      az = __builtin_amdgcn_mfma_f32_16x16x32_bf16(axc, xz, az, 0,0,0);
      az = __builtin_amdgcn_mfma_f32_16x16x32_bf16(ah0, whf[0][4+j], az, 0,0,0);
      az = __builtin_amdgcn_mfma_f32_16x16x32_bf16(ah1, whf[1][4+j], az, 0,0,0);
      f32x4 an = (f32x4){bxn_[j],bxn_[j],bxn_[j],bxn_[j]};
      an = __builtin_amdgcn_mfma_f32_16x16x32_bf16(axc, xn, an, 0,0,0);
      f32x4 ah = (f32x4){bhn_[j],bhn_[j],bhn_[j],bhn_[j]};
      ah = __builtin_amdgcn_mfma_f32_16x16x32_bf16(ah0, whf[0][8+j], ah, 0,0,0);
      ah = __builtin_amdgcn_mfma_f32_16x16x32_bf16(ah1, whf[1][8+j], ah, 0,0,0);
      #pragma unroll
      for (int i=0;i<4;++i){
        float r  = sigm(ar[i]);
        float z  = sigm(az[i]);
        float nn = tanh_(an[i] + r * ah[i]);
        float h  = fmaf(z, hprev[j][i]-nn, nn);
        hprev[j][i] = h;
        vmax[j][i] = fmaxf(vmax[j][i], h);
        hb[wave][quad*4+i][j*16+ln16] = f2bf(h);
      }
    }
    LDS_WAIT();
    axc = axn;
  }
  #pragma unroll
  for (int j=0;j<4;++j)
    #pragma unroll
    for (int i=0;i<4;++i)
      rnn[(size_t)(rowbase + quad*4 + i)*64 + j*16 + ln16] = vmax[j][i];
}

// ---------------------------------------------------------------------------
// Fused 2-layer GCN MLP via MFMA (unchanged).
// ---------------------------------------------------------------------------
__global__ __launch_bounds__(256, 2) void mlp2_kernel(
    const float* __restrict__ x,            // [BN][64] f32
    const int* __restrict__ ntid,           // [NN]
    const float* __restrict__ emb,          // [3][16]
    const float* __restrict__ W1,           // [80][64]
    const float* __restrict__ b1,           // [64]
    const float* __restrict__ W2,           // [64][64]
    const float* __restrict__ b2,           // [64]
    unsigned short* __restrict__ out)       // [BN][64] bf16
{
  __shared__ __attribute__((aligned(16))) unsigned short W1T[64][96];
  __shared__ __attribute__((aligned(16))) unsigned short W2T[64][72];
  __shared__ __attribute__((aligned(16))) unsigned short hb[4][16][72];
  __shared__ float sb1[64], sb2[64];
  int tid = threadIdx.x;
  for (int i=tid;i<80*64;i+=256){ int k=i>>6, n=i&63; W1T[n][k]=f2bf(W1[i]); }
  for (int i=tid;i<64*16;i+=256){ int n=i>>4, k=80+(i&15); W1T[n][k]=0; }
  for (int i=tid;i<64*64;i+=256){ int k=i>>6, n=i&63; W2T[n][k]=f2bf(W2[i]); }
  if (tid<64){ sb1[tid]=b1[tid]; sb2[tid]=b2[tid]; }
  __syncthreads();

  int wave = tid>>6, lane = tid&63, ln16 = lane&15, quad = lane>>4;
  int row0 = blockIdx.x*64 + wave*16;
  int r_ = row0 + ln16;
  const float* xr = x + (size_t)r_*64;
  bf16x8 a0 = ld8f(xr + quad*8);
  bf16x8 a1 = ld8f(xr + 32 + quad*8);
  int id = ntid[r_ % NN];
  bf16x8 a2 = (quad<2) ? ld8f(emb + id*16 + quad*8) : zero8();

  f32x4 acc[4];
  #pragma unroll
  for (int nt=0;nt<4;++nt){
    float bb = sb1[nt*16+ln16];
    acc[nt] = (f32x4){bb,bb,bb,bb};
    acc[nt] = __builtin_amdgcn_mfma_f32_16x16x32_bf16(a0, ld8bf(&W1T[nt*16+ln16][quad*8]),    acc[nt], 0,0,0);
    acc[nt] = __builtin_amdgcn_mfma_f32_16x16x32_bf16(a1, ld8bf(&W1T[nt*16+ln16][32+quad*8]), acc[nt], 0,0,0);
    acc[nt] = __builtin_amdgcn_mfma_f32_16x16x32_bf16(a2, ld8bf(&W1T[nt*16+ln16][64+quad*8]), acc[nt], 0,0,0);
  }
  #pragma unroll
  for (int nt=0;nt<4;++nt)
    #pragma unroll
    for (int i=0;i<4;++i)
      hb[wave][quad*4+i][nt*16+ln16] = f2bf(lrelu(acc[nt][i]));
  LDS_WAIT();
  bf16x8 h0 = ld8bf(&hb[wave][ln16][quad*8]);
  bf16x8 h1 = ld8bf(&hb[wave][ln16][32+quad*8]);
  f32x4 acc2[4];
  #pragma unroll
  for (int nt=0;nt<4;++nt){
    float bb = sb2[nt*16+ln16];
    acc2[nt] = (f32x4){bb,bb,bb,bb};
    acc2[nt] = __builtin_amdgcn_mfma_f32_16x16x32_bf16(h0, ld8bf(&W2T[nt*16+ln16][quad*8]),    acc2[nt], 0,0,0);
    acc2[nt] = __builtin_amdgcn_mfma_f32_16x16x32_bf16(h1, ld8bf(&W2T[nt*16+ln16][32+quad*8]), acc2[nt], 0,0,0);
  }
  #pragma unroll
  for (int nt=0;nt<4;++nt)
    #pragma unroll
    for (int i=0;i<4;++i)
      out[(size_t)(row0+quad*4+i)*64 + nt*16+ln16] = f2bf(lrelu(acc2[nt][i]));
}

// ---------------------------------------------------------------------------
// uv via MFMA (unchanged).
// ---------------------------------------------------------------------------
__global__ __launch_bounds__(256, 2) void uv_kernel(
    const float* __restrict__ x,            // [BN][64] f32
    const float* __restrict__ W1,           // [128][64]
    unsigned short* __restrict__ uvp)       // [BN][128] bf16
{
  __shared__ __attribute__((aligned(16))) unsigned short WT[128][72];
  int tid=threadIdx.x;
  for (int i=tid;i<64*64;i+=256){
    int k=i>>6, n=i&63;
    WT[n][k]    = f2bf(W1[i]);
    WT[64+n][k] = f2bf(W1[64*64 + i]);
  }
  __syncthreads();
  int wave=tid>>6, lane=tid&63, ln16=lane&15, quad=lane>>4;
  int row0 = blockIdx.x*64 + wave*16;
  const float* xr = x + (size_t)(row0+ln16)*64;
  bf16x8 a0 = ld8f(xr + quad*8);
  bf16x8 a1 = ld8f(xr + 32 + quad*8);
  f32x4 acc[8];
  #pragma unroll
  for (int nt=0;nt<8;++nt){
    acc[nt] = (f32x4){0.f,0.f,0.f,0.f};
    acc[nt] = __builtin_amdgcn_mfma_f32_16x16x32_bf16(a0, ld8bf(&WT[nt*16+ln16][quad*8]),    acc[nt], 0,0,0);
    acc[nt] = __builtin_amdgcn_mfma_f32_16x16x32_bf16(a1, ld8bf(&WT[nt*16+ln16][32+quad*8]), acc[nt], 0,0,0);
  }
  #pragma unroll
  for (int nt=0;nt<8;++nt)
    #pragma unroll
    for (int i=0;i<4;++i)
      uvp[(size_t)(row0+quad*4+i)*128 + nt*16+ln16] = f2bf(acc[nt][i]);
}

// ---------------------------------------------------------------------------
// CSR build: counting sort by dst; fill gathers edge_attr into CSR order.
// ---------------------------------------------------------------------------
__global__ __launch_bounds__(256) void count_kernel(const int* __restrict__ ei, int* __restrict__ counts){
  int e = blockIdx.x*256+threadIdx.x;
  atomicAdd(&counts[ei[NE+e]], 1);
}
// 2-barrier scan: each wave serially scans a 640-elem segment (LDS-buffered).
__global__ __launch_bounds__(1024) void scan_kernel(const int* __restrict__ counts,
                                                    int* __restrict__ rowptr, int* __restrict__ cursor){
  __shared__ int incl[10240];
  __shared__ int wsum[16];
  int tid=threadIdx.x, wave=tid>>6, lane=tid&63;
  int base = wave*640;
  int carry=0;
  #pragma unroll
  for (int c=0;c<10;++c){
    int i = base + c*64 + lane;
    int v = (i<NN)? counts[i] : 0;
    int s = v;
    #pragma unroll
    for (int off=1;off<64;off<<=1){
      int t_ = __shfl_up(s, off);
      if (lane>=off) s += t_;
    }
    s += carry;
    incl[base + c*64 + lane] = s;
    carry = __shfl(s, 63);
  }
  if (lane==63) wsum[wave]=carry;
  __syncthreads();
  if (wave==0){
    int w_ = (lane<16)? wsum[lane]:0;
    #pragma unroll
    for (int off=1;off<16;off<<=1){
      int t_ = __shfl_up(w_, off);
      if (lane>=off) w_ += t_;
    }
    if (lane<16) wsum[lane]=w_;   // inclusive prefix of wave sums
  }
  __syncthreads();
  int woff = (wave>0)? wsum[wave-1] : 0;
  #pragma unroll
  for (int c=0;c<10;++c){
    int i = base + c*64 + lane;
    if (i<NN){
      int excl = incl[i] + woff - counts[i];
      rowptr[i]=excl; cursor[i]=excl;
    }
  }
  if (tid==0) rowptr[NN]=wsum[15];
}
__global__ __launch_bounds__(256) void fill_kernel(const int* __restrict__ ei,
                                                   const float* __restrict__ ea,
                                                   int* __restrict__ cursor,
                                                   int* __restrict__ ssrc,
                                                   float* __restrict__ wcsr){
  int e = blockIdx.x*256+threadIdx.x;
  int d = ei[NE+e];
  int pos = atomicAdd(&cursor[d],1);
  ssrc[pos]=ei[e];
  wcsr[pos]=ea[e];
}

// out[b,n,:] = x[b,n,:] + sum_{e: dst=n} xin[b,src(e),:] * w(b,p)
// 256-thread blocks, 4 consecutive (batch-major) bids; batch-phase L2
// residency. Quarter-wave edge layout, unroll x4 (4 outstanding gathers).
// ---------------------------------------------------------------------------
__global__ __launch_bounds__(256) void aggr_kernel(
    const float* x,                        // [BN][64] f32
    const unsigned short* __restrict__ xin,// [BN][64] bf16 (messages)
    const int* __restrict__ rowptr,
    const int* __restrict__ ssrc,          // [NE] src sorted by dst
    const float* __restrict__ wp,          // p-indexed weights
    int bstride,
    float* out)                            // [BN][64] f32
{
  int tid=threadIdx.x;
  int wave=tid>>6, lane=tid&63;
  int sub=lane>>4, l=lane&15;
  int bid = blockIdx.x*4 + wave;           // batch-major
  int b = bid / NN, n = bid - b*NN;
  int p0 = rowptr[n], p1 = rowptr[n+1];
  const unsigned short* xb_ = xin + (size_t)b*NN*64;
  const float* wb = wp + (size_t)b*bstride;
  float a0=0.f, a1=0.f, a2=0.f, a3=0.f;
  #pragma unroll 4
  for (int p=p0+sub; p<p1; p+=4){
    int s = ssrc[p];
    float w = wb[p];
    uint2 m = *(const uint2*)(xb_ + (size_t)s*64 + l*4);
    a0 += bf2f((unsigned short)(m.x & 0xffffu)) * w;
    a1 += bf2f((unsigned short)(m.x >> 16)) * w;
    a2 += bf2f((unsigned short)(m.y & 0xffffu)) * w;
    a3 += bf2f((unsigned short)(m.y >> 16)) * w;
  }
  a0 += __shfl_xor(a0,16); a0 += __shfl_xor(a0,32);
  a1 += __shfl_xor(a1,16); a1 += __shfl_xor(a1,32);
  a2 += __shfl_xor(a2,16); a2 += __shfl_xor(a2,32);
  a3 += __shfl_xor(a3,16); a3 += __shfl_xor(a3,32);
  if (sub==0){
    float4 base = *(const float4*)(x + (size_t)bid*64 + l*4);
    float4 o; o.x=base.x+a0; o.y=base.y+a1; o.z=base.z+a2; o.w=base.w+a3;
    *(float4*)(out + (size_t)bid*64 + l*4) = o;
  }
}

// Last aggregation fused with both FC heads: y = (x+aggr)@Wg + rnn@Wr + biases.
// ---------------------------------------------------------------------------
__global__ __launch_bounds__(256) void aggr_final_kernel(
    const float* x,                        // [BN][64] f32 (xg input)
    const unsigned short* __restrict__ xin,// [BN][64] bf16
    const int* __restrict__ rowptr,
    const int* __restrict__ ssrc,
    const float* __restrict__ wp,          // gate, stride NE
    const float* __restrict__ rnn,         // [BN][64]
    const float* __restrict__ Wr, const float* __restrict__ br,
    const float* __restrict__ Wg, const float* __restrict__ bg,
    float* __restrict__ out)               // [BN][7]
{
  __shared__ float sWr[448], sWg[448], sb[7];
  int tid=threadIdx.x;
  for (int i=tid;i<448;i+=256){ sWr[i]=Wr[i]; sWg[i]=Wg[i]; }
  if (tid<7) sb[tid]=br[tid]+bg[tid];
  __syncthreads();
  int wave=tid>>6, lane=tid&63;
  int sub=lane>>4, l=lane&15;
  int bid = blockIdx.x*4 + wave;
  int b = bid / NN, n = bid - b*NN;
  int p0 = rowptr[n], p1 = rowptr[n+1];
  const unsigned short* xb_ = xin + (size_t)b*NN*64;
  const float* wb = wp + (size_t)b*NE;
  float a0=0.f, a1=0.f, a2=0.f, a3=0.f;
  #pragma unroll 4
  for (int p=p0+sub; p<p1; p+=4){
    int s = ssrc[p];
    float w = wb[p];
    uint2 m = *(const uint2*)(xb_ + (size_t)s*64 + l*4);
    a0 += bf2f((unsigned short)(m.x & 0xffffu)) * w;
    a1 += bf2f((unsigned short)(m.x >> 16)) * w;
    a2 += bf2f((unsigned short)(m.y & 0xffffu)) * w;
    a3 += bf2f((unsigned short)(m.y >> 16)) * w;
  }
  a0 += __shfl_xor(a0,16); a0 += __shfl_xor(a0,32);
  a1 += __shfl_xor(a1,16); a1 += __shfl_xor(a1,32);
  a2 += __shfl_xor(a2,16); a2 += __shfl_xor(a2,32);
  a3 += __shfl_xor(a3,16); a3 += __shfl_xor(a3,32);
  if (sub==0){
    float4 base = *(const float4*)(x + (size_t)bid*64 + l*4);
    float o0=base.x+a0, o1=base.y+a1, o2=base.z+a2, o3=base.w+a3;
    float4 rr = *(const float4*)(rnn + (size_t)bid*64 + l*4);
    float part[7];
    #pragma unroll
    for (int q=0;q<7;++q)
      part[q] = o0*sWg[(l*4+0)*7+q] + o1*sWg[(l*4+1)*7+q]
              + o2*sWg[(l*4+2)*7+q] + o3*sWg[(l*4+3)*7+q]
              + rr.x*sWr[(l*4+0)*7+q] + rr.y*sWr[(l*4+1)*7+q]
              + rr.z*sWr[(l*4+2)*7+q] + rr.w*sWr[(l*4+3)*7+q];
    #pragma unroll
    for (int q=0;q<7;++q){
      part[q] += __shfl_xor(part[q],1);
      part[q] += __shfl_xor(part[q],2);
      part[q] += __shfl_xor(part[q],4);
      part[q] += __shfl_xor(part[q],8);
    }
    if (l==0){
      #pragma unroll
      for (int q=0;q<7;++q) out[(size_t)bid*7+q] = part[q] + sb[q];
    }
  }
}

// ---------------------------------------------------------------------------
// CSR-ordered edge gate (256-thread blocks, 4 bids).
// ---------------------------------------------------------------------------
__global__ __launch_bounds__(256) void gate_kernel(
    const unsigned short* __restrict__ uvp, // [BN][128] bf16
    const int* __restrict__ rowptr,
    const int* __restrict__ ssrc,
    const float* __restrict__ b1,           // [64]
    const float* __restrict__ W2,           // [64]
    const float* __restrict__ b2,           // [1]
    float* __restrict__ gate)               // [B*E] f32, p-indexed
{
  int tid=threadIdx.x;
  int wave=tid>>6, lane=tid&63;
  int sub=lane>>4, l=lane&15;
  int bid = blockIdx.x*4 + wave;
  int b = bid / NN, n = bid - b*NN;
  int p0 = rowptr[n], p1 = rowptr[n+1];
  const unsigned short* ub = uvp + (size_t)b*NN*128;
  uint2 vu = *(const uint2*)(ub + (size_t)n*128 + 64 + l*4);
  float v0=bf2f((unsigned short)(vu.x&0xffffu)), v1=bf2f((unsigned short)(vu.x>>16));
  float v2=bf2f((unsigned short)(vu.y&0xffffu)), v3=bf2f((unsigned short)(vu.y>>16));
  float4 bb = *(const float4*)(b1 + l*4);
  float4 ww = *(const float4*)(W2 + l*4);
  float b2v = b2[0];
  float* gb = gate + (size_t)b*NE;
  #pragma unroll 4
  for (int p=p0+sub; p<p1; p+=4){
    int s = ssrc[p];
    uint2 uu = *(const uint2*)(ub + (size_t)s*128 + l*4);
    float h0 = lrelu(bf2f((unsigned short)(uu.x&0xffffu)) + v0 + bb.x);
    float h1 = lrelu(bf2f((unsigned short)(uu.x>>16))     + v1 + bb.y);
    float h2 = lrelu(bf2f((unsigned short)(uu.y&0xffffu)) + v2 + bb.z);
    float h3 = lrelu(bf2f((unsigned short)(uu.y>>16))     + v3 + bb.w);
    float part = h0*ww.x + h1*ww.y + h2*ww.z + h3*ww.w;
    part += __shfl_xor(part,1);
    part += __shfl_xor(part,2);
    part += __shfl_xor(part,4);
    part += __shfl_xor(part,8);
    if (l==0){
      float g = part + b2v;
      gb[p] = g>0.f ? g : 0.f;
    }
  }
}

// ---------------------------------------------------------------------------
extern "C" void kernel_launch(void* const* d_in, const int* in_sizes, int n_in,
                              void* d_out, int out_size, void* d_ws, size_t ws_size,
                              hipStream_t stream)
{
  (void)in_sizes; (void)n_in; (void)out_size; (void)ws_size;
  const float* input_day = (const float*)d_in[0];
  const int* ei    = (const int*)d_in[1];
  const int* ntid  = (const int*)d_in[2];
  const float* edge_attr = (const float*)d_in[3];
  const float* gWx = (const float*)d_in[4];
  const float* gWh = (const float*)d_in[5];
  const float* gbx = (const float*)d_in[6];
  const float* gbh = (const float*)d_in[7];
  const float* rW  = (const float*)d_in[8];
  const float* rb  = (const float*)d_in[9];
  const float* eemb= (const float*)d_in[10];
  const float* gemb= (const float*)d_in[11];
  const float* ec0W1=(const float*)d_in[12];
  const float* ec0b1=(const float*)d_in[13];
  const float* ec0W2=(const float*)d_in[14];
  const float* ec0b2=(const float*)d_in[15];
  const float* ec1W1=(const float*)d_in[16];
  const float* ec1b1=(const float*)d_in[17];
  const float* ec1W2=(const float*)d_in[18];
  const float* ec1b2=(const float*)d_in[19];
  const float* gc0W1=(const float*)d_in[20];
  const float* gc0b1=(const float*)d_in[21];
  const float* gc0W2=(const float*)d_in[22];
  const float* gc0b2=(const float*)d_in[23];
  const float* gc1W1=(const float*)d_in[24];
  const float* gc1b1=(const float*)d_in[25];
  const float* gc1W2=(const float*)d_in[26];
  const float* gc1b2=(const float*)d_in[27];
  const float* efmW1=(const float*)d_in[28];
  const float* efmb1=(const float*)d_in[29];
  const float* efmW2=(const float*)d_in[30];
  const float* efmb2=(const float*)d_in[31];
  const float* gcnW =(const float*)d_in[32];
  const float* gcnb =(const float*)d_in[33];

  // Workspace layout — ~43.6 MB (known-good envelope)
  char* ws = (char*)d_ws;
  float*          rnn = (float*)(ws);                      // 10,240,000 B
  float*          xe  = (float*)(ws + 10240000);           // 10,240,000 B
  unsigned short* xin = (unsigned short*)(ws + 20480000);  //  5,120,000 B
  unsigned short* uvp = (unsigned short*)(ws + 25600000);  // 10,240,000 B
  float*          gat = (float*)(ws + 35840000);           //  5,120,000 B (p-indexed)
  int* rowptr= (int*)(ws + 40960000);                      //     40,004 B
  int* cursor= (int*)(ws + 41000064);                      //     40,000 B
  int* counts= (int*)(ws + 41040064);                      //     40,000 B
  int*   ssrc= (int*)(ws + 41080064);                      //  1,280,000 B
  float* wcsr= (float*)(ws + 42360064);                    //  1,280,000 B -> 43,640,064

  // CSR build (ws re-poisoned before every launch: rebuild each call)
  hipMemsetAsync(counts, 0, NN*sizeof(int), stream);
  count_kernel<<<NE/256, 256, 0, stream>>>(ei, counts);
  scan_kernel<<<1, 1024, 0, stream>>>(counts, rowptr, cursor);
  fill_kernel<<<NE/256, 256, 0, stream>>>(ei, edge_attr, cursor, ssrc, wcsr);

  // GRU encoder + max over time (500 blocks x 80 rows: balanced 2 blocks/CU)
  gru_kernel<<<500, 320, 0, stream>>>(input_day, gWx, gWh, gbx, gbh, rnn);

  // EdgeNet: 2 GCN convs with static edge_attr weights (CSR-ordered)
  mlp2_kernel<<<625, 256, 0, stream>>>(rnn, ntid, eemb, ec0W1, ec0b1, ec0W2, ec0b2, xin);
  aggr_kernel<<<BN/4, 256, 0, stream>>>(rnn, xin, rowptr, ssrc, wcsr, 0, xe);
  mlp2_kernel<<<625, 256, 0, stream>>>(xe, ntid, eemb, ec1W1, ec1b1, ec1W2, ec1b2, xin);
  aggr_kernel<<<BN/4, 256, 0, stream>>>(xe, xin, rowptr, ssrc, wcsr, 0, xe);

  // edge gate (CSR-ordered, p-indexed output)
  uv_kernel<<<625, 256, 0, stream>>>(xe, efmW1, uvp);
  gate_kernel<<<BN/4, 256, 0, stream>>>(uvp, rowptr, ssrc, efmb1, efmW2, efmb2, gat);

  // Main GCN: 2 convs with learned per-(b,p) gates (xe reused as x_g)
  mlp2_kernel<<<625, 256, 0, stream>>>(rnn, ntid, gemb, gc0W1, gc0b1, gc0W2, gc0b2, xin);
  aggr_kernel<<<BN/4, 256, 0, stream>>>(rnn, xin, rowptr, ssrc, gat, NE, xe);
  mlp2_kernel<<<625, 256, 0, stream>>>(xe, ntid, gemb, gc1W1, gc1b1, gc1W2, gc1b2, xin);
  // last aggregation fused with both FC heads -> d_out
  aggr_final_kernel<<<BN/4, 256, 0, stream>>>(xe, xin, rowptr, ssrc, gat, rnn,
                                              rW, rb, gcnW, gcnb, (float*)d_out);
}

// Round 10
// 466.385 us; speedup vs baseline: 1.0442x; 1.0442x over previous
//
#include <hip/hip_runtime.h>
#include <hip/hip_bf16.h>

// Dims
#define NB 4
#define NN 10000
#define NE 320000
#define BN 40000   // NB*NN
#define NL 7

typedef float f32x4 __attribute__((ext_vector_type(4)));
typedef __bf16 bf16x8 __attribute__((ext_vector_type(8)));

__device__ __forceinline__ float bf2f(unsigned short u){
  unsigned x = ((unsigned)u) << 16;
  return __builtin_bit_cast(float, x);
}
__device__ __forceinline__ unsigned short f2bf(float f){
  unsigned u = __builtin_bit_cast(unsigned, f);
  u += 0x7fffu + ((u >> 16) & 1u);
  return (unsigned short)(u >> 16);
}
__device__ __forceinline__ __bf16 f2b(float f){
  return __builtin_bit_cast(__bf16, f2bf(f));
}
__device__ __forceinline__ bf16x8 zero8(){
  uint4 z = make_uint4(0u,0u,0u,0u);
  return __builtin_bit_cast(bf16x8, z);
}
__device__ __forceinline__ bf16x8 ld8bf(const unsigned short* p){
  uint4 u = *(const uint4*)p;
  return __builtin_bit_cast(bf16x8, u);
}
__device__ __forceinline__ bf16x8 ld8f(const float* p){
  float4 a = *(const float4*)p;
  float4 b = *(const float4*)(p+4);
  bf16x8 r;
  r[0]=f2b(a.x); r[1]=f2b(a.y); r[2]=f2b(a.z); r[3]=f2b(a.w);
  r[4]=f2b(b.x); r[5]=f2b(b.y); r[6]=f2b(b.z); r[7]=f2b(b.w);
  return r;
}
__device__ __forceinline__ float frcp(float x){ return __builtin_amdgcn_rcpf(x); }
__device__ __forceinline__ float sigm(float x){ return frcp(1.f+__expf(-x)); }
__device__ __forceinline__ float tanh_(float x){ return 1.f - 2.f*frcp(__expf(2.f*x)+1.f); }
__device__ __forceinline__ float lrelu(float x){ return x > 0.f ? x : 0.01f*x; }

#define LDS_WAIT() asm volatile("s_waitcnt lgkmcnt(0)" ::: "memory")

// ---------------------------------------------------------------------------
// GRU: fused 16 steps, 1 wave per 16 (b,n) rows. hb wave-private; wave-local
// waitcnt ordering. 625 blocks x 4 waves — measured optimum (78 us, r8).
// MEASURED DEAD ENDS: Wx-fragment hoist -> VGPR spill (r7, 107 us);
// 320-thr/5-wave blocks -> per-SIMD wave imbalance (r9, 95 us). Total waves
// 2500 > 2048 SIMD slots: some SIMD always carries 3 waves; this config
// balances them best.
// ---------------------------------------------------------------------------
__global__ __launch_bounds__(256, 2) void gru_kernel(
    const float* __restrict__ xd,   // [BN][256] f32 (T*DIN)
    const float* __restrict__ Wx,   // [16][192]
    const float* __restrict__ Wh,   // [64][192]
    const float* __restrict__ bx,   // [192]
    const float* __restrict__ bh,   // [192]
    float* __restrict__ rnn)        // [BN][64] f32 (max over T)
{
  __shared__ __attribute__((aligned(16))) unsigned short WhT[192][72];
  __shared__ __attribute__((aligned(16))) unsigned short WxT[192][40]; // k 16..31 zero
  __shared__ __attribute__((aligned(16))) unsigned short hb[4][16][72];
  int tid = threadIdx.x;
  int wave = tid >> 6, lane = tid & 63;
  int ln16 = lane & 15, quad = lane >> 4;

  for (int i = tid; i < 64*192; i += 256){
    int k = i / 192, n = i - k*192;
    WhT[n][k] = f2bf(Wh[i]);
  }
  for (int i = tid; i < 16*192; i += 256){
    int k = i / 192, n = i - k*192;
    WxT[n][k] = f2bf(Wx[i]);
    WxT[n][16+k] = 0;
  }
  for (int i = tid; i < 4*16*72; i += 256) ((unsigned short*)hb)[i] = 0;
  __syncthreads();   // the only block barrier

  int rowbase = blockIdx.x * 64 + wave * 16;

  bf16x8 whf[2][12];
  #pragma unroll
  for (int kt=0; kt<2; ++kt)
    #pragma unroll
    for (int nt=0; nt<12; ++nt)
      whf[kt][nt] = ld8bf(&WhT[nt*16 + ln16][kt*32 + quad*8]);

  float br_[4], bz_[4], bxn_[4], bhn_[4];
  #pragma unroll
  for (int j=0;j<4;++j){
    br_[j]  = bx[j*16+ln16]     + bh[j*16+ln16];
    bz_[j]  = bx[(4+j)*16+ln16] + bh[(4+j)*16+ln16];
    bxn_[j] = bx[(8+j)*16+ln16];
    bhn_[j] = bh[(8+j)*16+ln16];
  }

  f32x4 hprev[4], vmax[4];
  #pragma unroll
  for (int j=0;j<4;++j){
    hprev[j] = (f32x4){0.f,0.f,0.f,0.f};
    vmax[j]  = (f32x4){-1e30f,-1e30f,-1e30f,-1e30f};
  }

  const float* xrow = xd + (size_t)(rowbase + ln16) * 256;
  unsigned short* hrow = &hb[wave][ln16][0];

  bf16x8 axc = (quad < 2) ? ld8f(xrow + quad*8) : zero8();

  for (int t = 0; t < 16; ++t){
    bf16x8 axn = (t < 15 && quad < 2) ? ld8f(xrow + (t+1)*16 + quad*8) : zero8();
    bf16x8 ah0 = ld8bf(hrow + quad*8);
    bf16x8 ah1 = ld8bf(hrow + 32 + quad*8);

    #pragma unroll
    for (int j=0;j<4;++j){
      bf16x8 xr = ld8bf(&WxT[j*16+ln16][quad*8]);
      bf16x8 xz = ld8bf(&WxT[(4+j)*16+ln16][quad*8]);
      bf16x8 xn = ld8bf(&WxT[(8+j)*16+ln16][quad*8]);
      f32x4 ar = (f32x4){br_[j],br_[j],br_[j],br_[j]};
      ar = __builtin_amdgcn_mfma_f32_16x16x32_bf16(axc, xr, ar, 0,0,0);
      ar = __builtin_amdgcn_mfma_f32_16x16x32_bf16(ah0, whf[0][j], ar, 0,0,0);
      ar = __builtin_amdgcn_mfma_f32_16x16x32_bf16(ah1, whf[1][j], ar, 0,0,0);
      f32x4 az = (f32x4){bz_[j],bz_[j],bz_[j],bz_[j]};
      az = __builtin_amdgcn_mfma_f32_16x16x32_bf16(axc, xz, az, 0,0,0);
      az = __builtin_amdgcn_mfma_f32_16x16x32_bf16(ah0, whf[0][4+j], az, 0,0,0);
      az = __builtin_amdgcn_mfma_f32_16x16x32_bf16(ah1, whf[1][4+j], az, 0,0,0);
      f32x4 an = (f32x4){bxn_[j],bxn_[j],bxn_[j],bxn_[j]};
      an = __builtin_amdgcn_mfma_f32_16x16x32_bf16(axc, xn, an, 0,0,0);
      f32x4 ah = (f32x4){bhn_[j],bhn_[j],bhn_[j],bhn_[j]};
      ah = __builtin_amdgcn_mfma_f32_16x16x32_bf16(ah0, whf[0][8+j], ah, 0,0,0);
      ah = __builtin_amdgcn_mfma_f32_16x16x32_bf16(ah1, whf[1][8+j], ah, 0,0,0);
      #pragma unroll
      for (int i=0;i<4;++i){
        float r  = sigm(ar[i]);
        float z  = sigm(az[i]);
        float nn = tanh_(an[i] + r * ah[i]);
        float h  = fmaf(z, hprev[j][i]-nn, nn);
        hprev[j][i] = h;
        vmax[j][i] = fmaxf(vmax[j][i], h);
        hb[wave][quad*4+i][j*16+ln16] = f2bf(h);
      }
    }
    LDS_WAIT();
    axc = axn;
  }
  #pragma unroll
  for (int j=0;j<4;++j)
    #pragma unroll
    for (int i=0;i<4;++i)
      rnn[(size_t)(rowbase + quad*4 + i)*64 + j*16 + ln16] = vmax[j][i];
}

// ---------------------------------------------------------------------------
// Fused 2-layer GCN MLP via MFMA (unchanged).
// ---------------------------------------------------------------------------
__global__ __launch_bounds__(256, 2) void mlp2_kernel(
    const float* __restrict__ x,            // [BN][64] f32
    const int* __restrict__ ntid,           // [NN]
    const float* __restrict__ emb,          // [3][16]
    const float* __restrict__ W1,           // [80][64]
    const float* __restrict__ b1,           // [64]
    const float* __restrict__ W2,           // [64][64]
    const float* __restrict__ b2,           // [64]
    unsigned short* __restrict__ out)       // [BN][64] bf16
{
  __shared__ __attribute__((aligned(16))) unsigned short W1T[64][96];
  __shared__ __attribute__((aligned(16))) unsigned short W2T[64][72];
  __shared__ __attribute__((aligned(16))) unsigned short hb[4][16][72];
  __shared__ float sb1[64], sb2[64];
  int tid = threadIdx.x;
  for (int i=tid;i<80*64;i+=256){ int k=i>>6, n=i&63; W1T[n][k]=f2bf(W1[i]); }
  for (int i=tid;i<64*16;i+=256){ int n=i>>4, k=80+(i&15); W1T[n][k]=0; }
  for (int i=tid;i<64*64;i+=256){ int k=i>>6, n=i&63; W2T[n][k]=f2bf(W2[i]); }
  if (tid<64){ sb1[tid]=b1[tid]; sb2[tid]=b2[tid]; }
  __syncthreads();

  int wave = tid>>6, lane = tid&63, ln16 = lane&15, quad = lane>>4;
  int row0 = blockIdx.x*64 + wave*16;
  int r_ = row0 + ln16;
  const float* xr = x + (size_t)r_*64;
  bf16x8 a0 = ld8f(xr + quad*8);
  bf16x8 a1 = ld8f(xr + 32 + quad*8);
  int id = ntid[r_ % NN];
  bf16x8 a2 = (quad<2) ? ld8f(emb + id*16 + quad*8) : zero8();

  f32x4 acc[4];
  #pragma unroll
  for (int nt=0;nt<4;++nt){
    float bb = sb1[nt*16+ln16];
    acc[nt] = (f32x4){bb,bb,bb,bb};
    acc[nt] = __builtin_amdgcn_mfma_f32_16x16x32_bf16(a0, ld8bf(&W1T[nt*16+ln16][quad*8]),    acc[nt], 0,0,0);
    acc[nt] = __builtin_amdgcn_mfma_f32_16x16x32_bf16(a1, ld8bf(&W1T[nt*16+ln16][32+quad*8]), acc[nt], 0,0,0);
    acc[nt] = __builtin_amdgcn_mfma_f32_16x16x32_bf16(a2, ld8bf(&W1T[nt*16+ln16][64+quad*8]), acc[nt], 0,0,0);
  }
  #pragma unroll
  for (int nt=0;nt<4;++nt)
    #pragma unroll
    for (int i=0;i<4;++i)
      hb[wave][quad*4+i][nt*16+ln16] = f2bf(lrelu(acc[nt][i]));
  LDS_WAIT();
  bf16x8 h0 = ld8bf(&hb[wave][ln16][quad*8]);
  bf16x8 h1 = ld8bf(&hb[wave][ln16][32+quad*8]);
  f32x4 acc2[4];
  #pragma unroll
  for (int nt=0;nt<4;++nt){
    float bb = sb2[nt*16+ln16];
    acc2[nt] = (f32x4){bb,bb,bb,bb};
    acc2[nt] = __builtin_amdgcn_mfma_f32_16x16x32_bf16(h0, ld8bf(&W2T[nt*16+ln16][quad*8]),    acc2[nt], 0,0,0);
    acc2[nt] = __builtin_amdgcn_mfma_f32_16x16x32_bf16(h1, ld8bf(&W2T[nt*16+ln16][32+quad*8]), acc2[nt], 0,0,0);
  }
  #pragma unroll
  for (int nt=0;nt<4;++nt)
    #pragma unroll
    for (int i=0;i<4;++i)
      out[(size_t)(row0+quad*4+i)*64 + nt*16+ln16] = f2bf(lrelu(acc2[nt][i]));
}

// ---------------------------------------------------------------------------
// uv via MFMA (unchanged).
// ---------------------------------------------------------------------------
__global__ __launch_bounds__(256, 2) void uv_kernel(
    const float* __restrict__ x,            // [BN][64] f32
    const float* __restrict__ W1,           // [128][64]
    unsigned short* __restrict__ uvp)       // [BN][128] bf16
{
  __shared__ __attribute__((aligned(16))) unsigned short WT[128][72];
  int tid=threadIdx.x;
  for (int i=tid;i<64*64;i+=256){
    int k=i>>6, n=i&63;
    WT[n][k]    = f2bf(W1[i]);
    WT[64+n][k] = f2bf(W1[64*64 + i]);
  }
  __syncthreads();
  int wave=tid>>6, lane=tid&63, ln16=lane&15, quad=lane>>4;
  int row0 = blockIdx.x*64 + wave*16;
  const float* xr = x + (size_t)(row0+ln16)*64;
  bf16x8 a0 = ld8f(xr + quad*8);
  bf16x8 a1 = ld8f(xr + 32 + quad*8);
  f32x4 acc[8];
  #pragma unroll
  for (int nt=0;nt<8;++nt){
    acc[nt] = (f32x4){0.f,0.f,0.f,0.f};
    acc[nt] = __builtin_amdgcn_mfma_f32_16x16x32_bf16(a0, ld8bf(&WT[nt*16+ln16][quad*8]),    acc[nt], 0,0,0);
    acc[nt] = __builtin_amdgcn_mfma_f32_16x16x32_bf16(a1, ld8bf(&WT[nt*16+ln16][32+quad*8]), acc[nt], 0,0,0);
  }
  #pragma unroll
  for (int nt=0;nt<8;++nt)
    #pragma unroll
    for (int i=0;i<4;++i)
      uvp[(size_t)(row0+quad*4+i)*128 + nt*16+ln16] = f2bf(acc[nt][i]);
}

// ---------------------------------------------------------------------------
// CSR build: counting sort by dst; fill gathers edge_attr into CSR order.
// ---------------------------------------------------------------------------
__global__ __launch_bounds__(256) void count_kernel(const int* __restrict__ ei, int* __restrict__ counts){
  int e = blockIdx.x*256+threadIdx.x;
  atomicAdd(&counts[ei[NE+e]], 1);
}
// 2-barrier scan: each wave serially scans a 640-elem segment (LDS-buffered).
__global__ __launch_bounds__(1024) void scan_kernel(const int* __restrict__ counts,
                                                    int* __restrict__ rowptr, int* __restrict__ cursor){
  __shared__ int incl[10240];
  __shared__ int wsum[16];
  int tid=threadIdx.x, wave=tid>>6, lane=tid&63;
  int base = wave*640;
  int carry=0;
  #pragma unroll
  for (int c=0;c<10;++c){
    int i = base + c*64 + lane;
    int v = (i<NN)? counts[i] : 0;
    int s = v;
    #pragma unroll
    for (int off=1;off<64;off<<=1){
      int t_ = __shfl_up(s, off);
      if (lane>=off) s += t_;
    }
    s += carry;
    incl[base + c*64 + lane] = s;
    carry = __shfl(s, 63);
  }
  if (lane==63) wsum[wave]=carry;
  __syncthreads();
  if (wave==0){
    int w_ = (lane<16)? wsum[lane]:0;
    #pragma unroll
    for (int off=1;off<16;off<<=1){
      int t_ = __shfl_up(w_, off);
      if (lane>=off) w_ += t_;
    }
    if (lane<16) wsum[lane]=w_;   // inclusive prefix of wave sums
  }
  __syncthreads();
  int woff = (wave>0)? wsum[wave-1] : 0;
  #pragma unroll
  for (int c=0;c<10;++c){
    int i = base + c*64 + lane;
    if (i<NN){
      int excl = incl[i] + woff - counts[i];
      rowptr[i]=excl; cursor[i]=excl;
    }
  }
  if (tid==0) rowptr[NN]=wsum[15];
}
__global__ __launch_bounds__(256) void fill_kernel(const int* __restrict__ ei,
                                                   const float* __restrict__ ea,
                                                   int* __restrict__ cursor,
                                                   int* __restrict__ ssrc,
                                                   float* __restrict__ wcsr){
  int e = blockIdx.x*256+threadIdx.x;
  int d = ei[NE+e];
  int pos = atomicAdd(&cursor[d],1);
  ssrc[pos]=ei[e];
  wcsr[pos]=ea[e];
}

// out[b,n,:] = x[b,n,:] + sum_{e: dst=n} xin[b,src(e),:] * w(b,p)
// 256-thread blocks, 4 consecutive (batch-major) bids; batch-phase L2
// residency. Quarter-wave edge layout, unroll x4 (4 outstanding gathers).
// ---------------------------------------------------------------------------
__global__ __launch_bounds__(256) void aggr_kernel(
    const float* x,                        // [BN][64] f32
    const unsigned short* __restrict__ xin,// [BN][64] bf16 (messages)
    const int* __restrict__ rowptr,
    const int* __restrict__ ssrc,          // [NE] src sorted by dst
    const float* __restrict__ wp,          // p-indexed weights
    int bstride,
    float* out)                            // [BN][64] f32
{
  int tid=threadIdx.x;
  int wave=tid>>6, lane=tid&63;
  int sub=lane>>4, l=lane&15;
  int bid = blockIdx.x*4 + wave;           // batch-major
  int b = bid / NN, n = bid - b*NN;
  int p0 = rowptr[n], p1 = rowptr[n+1];
  const unsigned short* xb_ = xin + (size_t)b*NN*64;
  const float* wb = wp + (size_t)b*bstride;
  float a0=0.f, a1=0.f, a2=0.f, a3=0.f;
  #pragma unroll 4
  for (int p=p0+sub; p<p1; p+=4){
    int s = ssrc[p];
    float w = wb[p];
    uint2 m = *(const uint2*)(xb_ + (size_t)s*64 + l*4);
    a0 += bf2f((unsigned short)(m.x & 0xffffu)) * w;
    a1 += bf2f((unsigned short)(m.x >> 16)) * w;
    a2 += bf2f((unsigned short)(m.y & 0xffffu)) * w;
    a3 += bf2f((unsigned short)(m.y >> 16)) * w;
  }
  a0 += __shfl_xor(a0,16); a0 += __shfl_xor(a0,32);
  a1 += __shfl_xor(a1,16); a1 += __shfl_xor(a1,32);
  a2 += __shfl_xor(a2,16); a2 += __shfl_xor(a2,32);
  a3 += __shfl_xor(a3,16); a3 += __shfl_xor(a3,32);
  if (sub==0){
    float4 base = *(const float4*)(x + (size_t)bid*64 + l*4);
    float4 o; o.x=base.x+a0; o.y=base.y+a1; o.z=base.z+a2; o.w=base.w+a3;
    *(float4*)(out + (size_t)bid*64 + l*4) = o;
  }
}

// Last aggregation fused with both FC heads: y = (x+aggr)@Wg + rnn@Wr + biases.
// ---------------------------------------------------------------------------
__global__ __launch_bounds__(256) void aggr_final_kernel(
    const float* x,                        // [BN][64] f32 (xg input)
    const unsigned short* __restrict__ xin,// [BN][64] bf16
    const int* __restrict__ rowptr,
    const int* __restrict__ ssrc,
    const float* __restrict__ wp,          // gate, stride NE
    const float* __restrict__ rnn,         // [BN][64]
    const float* __restrict__ Wr, const float* __restrict__ br,
    const float* __restrict__ Wg, const float* __restrict__ bg,
    float* __restrict__ out)               // [BN][7]
{
  __shared__ float sWr[448], sWg[448], sb[7];
  int tid=threadIdx.x;
  for (int i=tid;i<448;i+=256){ sWr[i]=Wr[i]; sWg[i]=Wg[i]; }
  if (tid<7) sb[tid]=br[tid]+bg[tid];
  __syncthreads();
  int wave=tid>>6, lane=tid&63;
  int sub=lane>>4, l=lane&15;
  int bid = blockIdx.x*4 + wave;
  int b = bid / NN, n = bid - b*NN;
  int p0 = rowptr[n], p1 = rowptr[n+1];
  const unsigned short* xb_ = xin + (size_t)b*NN*64;
  const float* wb = wp + (size_t)b*NE;
  float a0=0.f, a1=0.f, a2=0.f, a3=0.f;
  #pragma unroll 4
  for (int p=p0+sub; p<p1; p+=4){
    int s = ssrc[p];
    float w = wb[p];
    uint2 m = *(const uint2*)(xb_ + (size_t)s*64 + l*4);
    a0 += bf2f((unsigned short)(m.x & 0xffffu)) * w;
    a1 += bf2f((unsigned short)(m.x >> 16)) * w;
    a2 += bf2f((unsigned short)(m.y & 0xffffu)) * w;
    a3 += bf2f((unsigned short)(m.y >> 16)) * w;
  }
  a0 += __shfl_xor(a0,16); a0 += __shfl_xor(a0,32);
  a1 += __shfl_xor(a1,16); a1 += __shfl_xor(a1,32);
  a2 += __shfl_xor(a2,16); a2 += __shfl_xor(a2,32);
  a3 += __shfl_xor(a3,16); a3 += __shfl_xor(a3,32);
  if (sub==0){
    float4 base = *(const float4*)(x + (size_t)bid*64 + l*4);
    float o0=base.x+a0, o1=base.y+a1, o2=base.z+a2, o3=base.w+a3;
    float4 rr = *(const float4*)(rnn + (size_t)bid*64 + l*4);
    float part[7];
    #pragma unroll
    for (int q=0;q<7;++q)
      part[q] = o0*sWg[(l*4+0)*7+q] + o1*sWg[(l*4+1)*7+q]
              + o2*sWg[(l*4+2)*7+q] + o3*sWg[(l*4+3)*7+q]
              + rr.x*sWr[(l*4+0)*7+q] + rr.y*sWr[(l*4+1)*7+q]
              + rr.z*sWr[(l*4+2)*7+q] + rr.w*sWr[(l*4+3)*7+q];
    #pragma unroll
    for (int q=0;q<7;++q){
      part[q] += __shfl_xor(part[q],1);
      part[q] += __shfl_xor(part[q],2);
      part[q] += __shfl_xor(part[q],4);
      part[q] += __shfl_xor(part[q],8);
    }
    if (l==0){
      #pragma unroll
      for (int q=0;q<7;++q) out[(size_t)bid*7+q] = part[q] + sb[q];
    }
  }
}

// ---------------------------------------------------------------------------
// CSR-ordered edge gate (256-thread blocks, 4 bids).
// ---------------------------------------------------------------------------
__global__ __launch_bounds__(256) void gate_kernel(
    const unsigned short* __restrict__ uvp, // [BN][128] bf16
    const int* __restrict__ rowptr,
    const int* __restrict__ ssrc,
    const float* __restrict__ b1,           // [64]
    const float* __restrict__ W2,           // [64]
    const float* __restrict__ b2,           // [1]
    float* __restrict__ gate)               // [B*E] f32, p-indexed
{
  int tid=threadIdx.x;
  int wave=tid>>6, lane=tid&63;
  int sub=lane>>4, l=lane&15;
  int bid = blockIdx.x*4 + wave;
  int b = bid / NN, n = bid - b*NN;
  int p0 = rowptr[n], p1 = rowptr[n+1];
  const unsigned short* ub = uvp + (size_t)b*NN*128;
  uint2 vu = *(const uint2*)(ub + (size_t)n*128 + 64 + l*4);
  float v0=bf2f((unsigned short)(vu.x&0xffffu)), v1=bf2f((unsigned short)(vu.x>>16));
  float v2=bf2f((unsigned short)(vu.y&0xffffu)), v3=bf2f((unsigned short)(vu.y>>16));
  float4 bb = *(const float4*)(b1 + l*4);
  float4 ww = *(const float4*)(W2 + l*4);
  float b2v = b2[0];
  float* gb = gate + (size_t)b*NE;
  #pragma unroll 4
  for (int p=p0+sub; p<p1; p+=4){
    int s = ssrc[p];
    uint2 uu = *(const uint2*)(ub + (size_t)s*128 + l*4);
    float h0 = lrelu(bf2f((unsigned short)(uu.x&0xffffu)) + v0 + bb.x);
    float h1 = lrelu(bf2f((unsigned short)(uu.x>>16))     + v1 + bb.y);
    float h2 = lrelu(bf2f((unsigned short)(uu.y&0xffffu)) + v2 + bb.z);
    float h3 = lrelu(bf2f((unsigned short)(uu.y>>16))     + v3 + bb.w);
    float part = h0*ww.x + h1*ww.y + h2*ww.z + h3*ww.w;
    part += __shfl_xor(part,1);
    part += __shfl_xor(part,2);
    part += __shfl_xor(part,4);
    part += __shfl_xor(part,8);
    if (l==0){
      float g = part + b2v;
      gb[p] = g>0.f ? g : 0.f;
    }
  }
}

// ---------------------------------------------------------------------------
extern "C" void kernel_launch(void* const* d_in, const int* in_sizes, int n_in,
                              void* d_out, int out_size, void* d_ws, size_t ws_size,
                              hipStream_t stream)
{
  (void)in_sizes; (void)n_in; (void)out_size; (void)ws_size;
  const float* input_day = (const float*)d_in[0];
  const int* ei    = (const int*)d_in[1];
  const int* ntid  = (const int*)d_in[2];
  const float* edge_attr = (const float*)d_in[3];
  const float* gWx = (const float*)d_in[4];
  const float* gWh = (const float*)d_in[5];
  const float* gbx = (const float*)d_in[6];
  const float* gbh = (const float*)d_in[7];
  const float* rW  = (const float*)d_in[8];
  const float* rb  = (const float*)d_in[9];
  const float* eemb= (const float*)d_in[10];
  const float* gemb= (const float*)d_in[11];
  const float* ec0W1=(const float*)d_in[12];
  const float* ec0b1=(const float*)d_in[13];
  const float* ec0W2=(const float*)d_in[14];
  const float* ec0b2=(const float*)d_in[15];
  const float* ec1W1=(const float*)d_in[16];
  const float* ec1b1=(const float*)d_in[17];
  const float* ec1W2=(const float*)d_in[18];
  const float* ec1b2=(const float*)d_in[19];
  const float* gc0W1=(const float*)d_in[20];
  const float* gc0b1=(const float*)d_in[21];
  const float* gc0W2=(const float*)d_in[22];
  const float* gc0b2=(const float*)d_in[23];
  const float* gc1W1=(const float*)d_in[24];
  const float* gc1b1=(const float*)d_in[25];
  const float* gc1W2=(const float*)d_in[26];
  const float* gc1b2=(const float*)d_in[27];
  const float* efmW1=(const float*)d_in[28];
  const float* efmb1=(const float*)d_in[29];
  const float* efmW2=(const float*)d_in[30];
  const float* efmb2=(const float*)d_in[31];
  const float* gcnW =(const float*)d_in[32];
  const float* gcnb =(const float*)d_in[33];

  // Workspace layout — ~43.6 MB (known-good envelope)
  char* ws = (char*)d_ws;
  float*          rnn = (float*)(ws);                      // 10,240,000 B
  float*          xe  = (float*)(ws + 10240000);           // 10,240,000 B
  unsigned short* xin = (unsigned short*)(ws + 20480000);  //  5,120,000 B
  unsigned short* uvp = (unsigned short*)(ws + 25600000);  // 10,240,000 B
  float*          gat = (float*)(ws + 35840000);           //  5,120,000 B (p-indexed)
  int* rowptr= (int*)(ws + 40960000);                      //     40,004 B
  int* cursor= (int*)(ws + 41000064);                      //     40,000 B
  int* counts= (int*)(ws + 41040064);                      //     40,000 B
  int*   ssrc= (int*)(ws + 41080064);                      //  1,280,000 B
  float* wcsr= (float*)(ws + 42360064);                    //  1,280,000 B -> 43,640,064

  // CSR build (ws re-poisoned before every launch: rebuild each call)
  hipMemsetAsync(counts, 0, NN*sizeof(int), stream);
  count_kernel<<<NE/256, 256, 0, stream>>>(ei, counts);
  scan_kernel<<<1, 1024, 0, stream>>>(counts, rowptr, cursor);
  fill_kernel<<<NE/256, 256, 0, stream>>>(ei, edge_attr, cursor, ssrc, wcsr);

  // GRU encoder + max over time (625 x 256: measured-optimal config, r8)
  gru_kernel<<<625, 256, 0, stream>>>(input_day, gWx, gWh, gbx, gbh, rnn);

  // EdgeNet: 2 GCN convs with static edge_attr weights (CSR-ordered)
  mlp2_kernel<<<625, 256, 0, stream>>>(rnn, ntid, eemb, ec0W1, ec0b1, ec0W2, ec0b2, xin);
  aggr_kernel<<<BN/4, 256, 0, stream>>>(rnn, xin, rowptr, ssrc, wcsr, 0, xe);
  mlp2_kernel<<<625, 256, 0, stream>>>(xe, ntid, eemb, ec1W1, ec1b1, ec1W2, ec1b2, xin);
  aggr_kernel<<<BN/4, 256, 0, stream>>>(xe, xin, rowptr, ssrc, wcsr, 0, xe);

  // edge gate (CSR-ordered, p-indexed output)
  uv_kernel<<<625, 256, 0, stream>>>(xe, efmW1, uvp);
  gate_kernel<<<BN/4, 256, 0, stream>>>(uvp, rowptr, ssrc, efmb1, efmW2, efmb2, gat);

  // Main GCN: 2 convs with learned per-(b,p) gates (xe reused as x_g)
  mlp2_kernel<<<625, 256, 0, stream>>>(rnn, ntid, gemb, gc0W1, gc0b1, gc0W2, gc0b2, xin);
  aggr_kernel<<<BN/4, 256, 0, stream>>>(rnn, xin, rowptr, ssrc, gat, NE, xe);
  mlp2_kernel<<<625, 256, 0, stream>>>(xe, ntid, gemb, gc1W1, gc1b1, gc1W2, gc1b2, xin);
  // last aggregation fused with both FC heads -> d_out
  aggr_final_kernel<<<BN/4, 256, 0, stream>>>(xe, xin, rowptr, ssrc, gat, rnn,
                                              rW, rb, gcnW, gcnb, (float*)d_out);
}